// Round 12
// baseline (376.502 us; speedup 1.0000x reference)
//
#include <hip/hip_runtime.h>
#include <hip/hip_bf16.h>

#define PI_F 3.14159265358979323846f
#define NBLK 256     // chunk count for count/scatter passes (scan width)
#define BSH 8        // coarse bucket = 256 dst nodes
#define BSZ 256      // nodes per bucket
#define SCAP 10240   // LDS edge staging capacity (mean 8192, +22 sigma)
#define SLDS 3072    // per-block csr staging for agg kernels (64 nodes, mean 2048, +22 sigma)

static inline size_t align256(size_t x) { return (x + 255) & ~size_t(255); }

typedef float v2f __attribute__((ext_vector_type(2)));
typedef unsigned uvec2 __attribute__((ext_vector_type(2)));   // native vectors: NT-load/store legal
typedef unsigned uvec4 __attribute__((ext_vector_type(4)));

// bf16 helpers (bit tricks; round-to-nearest via +0x8000)
__device__ __forceinline__ unsigned bfpack(float a, float b) {
    unsigned lo = (__float_as_uint(a) + 0x8000u) >> 16;
    unsigned hi = (__float_as_uint(b) + 0x8000u) & 0xFFFF0000u;
    return lo | hi;
}

// accumulate one 8B fp8 row-quarter (8 features) scaled by rs into acc[8]
__device__ __forceinline__ void f8acc(uvec2 q, float rs, float acc[8]) {
    v2f l0 = __builtin_amdgcn_cvt_pk_f32_fp8(q.x, false);
    v2f h0 = __builtin_amdgcn_cvt_pk_f32_fp8(q.x, true);
    v2f l1 = __builtin_amdgcn_cvt_pk_f32_fp8(q.y, false);
    v2f h1 = __builtin_amdgcn_cvt_pk_f32_fp8(q.y, true);
    acc[0] += rs * l0.x; acc[1] += rs * l0.y; acc[2] += rs * h0.x; acc[3] += rs * h0.y;
    acc[4] += rs * l1.x; acc[5] += rs * l1.y; acc[6] += rs * h1.x; acc[7] += rs * h1.y;
}

// ---------------- atomic-free bucketed CSR build ----------------

__global__ void __launch_bounds__(1024) count_kernel(
                             const int* __restrict__ dst, int* __restrict__ C,
                             int E, int CHUNK, int NB2) {
    extern __shared__ int hist[];   // NB2 ints
    for (int i = threadIdx.x; i < NB2; i += 1024) hist[i] = 0;
    __syncthreads();
    int s0 = blockIdx.x * CHUNK, s1 = min(s0 + CHUNK, E);
    for (int e = s0 + threadIdx.x; e < s1; e += 1024)
        atomicAdd(&hist[dst[e] >> BSH], 1);
    __syncthreads();
    for (int i = threadIdx.x; i < NB2; i += 1024)
        C[(size_t)blockIdx.x * NB2 + i] = hist[i];
}

// scan of C columns + fused graph-boundary index build (grids match: NB2 x 256)
__global__ void scan_blocks_kernel(int* __restrict__ C, int* __restrict__ colsum, int NB2,
                                   const int* __restrict__ batch, int* __restrict__ gstart,
                                   int n, int G) {
    __shared__ int s[256];
    int k = blockIdx.x;
    int b = threadIdx.x;
    int v = C[(size_t)b * NB2 + k];
    s[b] = v;
    __syncthreads();
    for (int off = 1; off < 256; off <<= 1) {
        int w = (b >= off) ? s[b - off] : 0;
        __syncthreads();
        s[b] += w;
        __syncthreads();
    }
    C[(size_t)b * NB2 + k] = s[b] - v;   // exclusive
    if (b == 255) colsum[k] = s[255];
    // fused gb: boundary detection for node index i
    int i = k * 256 + b;
    if (i < n) {
        int g = batch[i];
        if (i == 0) {
            for (int gg = 0; gg <= g; gg++) gstart[gg] = 0;
        } else {
            int gp = batch[i - 1];
            for (int gg = gp + 1; gg <= g; gg++) gstart[gg] = i;
        }
        if (i == n - 1) {
            for (int gg = g + 1; gg <= G; gg++) gstart[gg] = n;
        }
    }
}

__global__ void scan_totals_kernel(const int* __restrict__ colsum, int* __restrict__ bbase,
                                   int NB2, int E) {
    __shared__ int s[256];
    __shared__ int running;
    if (threadIdx.x == 0) running = 0;
    __syncthreads();
    for (int base = 0; base < NB2; base += 256) {
        int i = base + threadIdx.x;
        int v = (i < NB2) ? colsum[i] : 0;
        s[threadIdx.x] = v;
        __syncthreads();
        for (int off = 1; off < 256; off <<= 1) {
            int w = (threadIdx.x >= (unsigned)off) ? s[threadIdx.x - off] : 0;
            __syncthreads();
            s[threadIdx.x] += w;
            __syncthreads();
        }
        if (i < NB2) bbase[i] = running + s[threadIdx.x] - v;
        __syncthreads();
        if (threadIdx.x == 255) running += s[255];
        __syncthreads();
    }
    if (threadIdx.x == 0) bbase[NB2] = E;
}

__global__ void __launch_bounds__(1024) scatter_kernel(
                               const int* __restrict__ src, const int* __restrict__ dst,
                               const int* __restrict__ C, const int* __restrict__ bbase,
                               unsigned* __restrict__ bkt_data, int E, int CHUNK, int NB2) {
    extern __shared__ int ofs[];   // NB2 ints
    for (int i = threadIdx.x; i < NB2; i += 1024)
        ofs[i] = bbase[i] + C[(size_t)blockIdx.x * NB2 + i];
    __syncthreads();
    int s0 = blockIdx.x * CHUNK, s1 = min(s0 + CHUNK, E);
    for (int e = s0 + threadIdx.x; e < s1; e += 1024) {
        int d = dst[e];
        int p = atomicAdd(&ofs[d >> BSH], 1);   // LDS atomic only
        bkt_data[p] = ((unsigned)(d & (BSZ - 1)) << 17) | (unsigned)src[e];
    }
}

__global__ void __launch_bounds__(512) csr_build_kernel(
                                 const unsigned* __restrict__ bkt_data, const int* __restrict__ bbase,
                                 const float* __restrict__ x,
                                 unsigned* __restrict__ csr, int* __restrict__ e_start,
                                 float* __restrict__ dinv, float* __restrict__ xd,
                                 int N, int NB2) {
    __shared__ unsigned sdata[SCAP];
    __shared__ int hist[256];
    __shared__ int scn[256];
    __shared__ int bump[256];
    int tid = threadIdx.x;
    int b = blockIdx.x;
    int g0 = bbase[b], g1 = bbase[b + 1];
    int cnt = g1 - g0;
    bool fits = (cnt <= SCAP);
    if (tid < 256) hist[tid] = 0;
    __syncthreads();
    for (int i = tid; i < cnt; i += 512) {
        unsigned pk = bkt_data[g0 + i];
        if (fits) sdata[i] = pk;
        atomicAdd(&hist[pk >> 17], 1);
    }
    __syncthreads();
    int orig = (tid < 256) ? hist[tid] : 0;
    if (tid < 256) scn[tid] = orig;
    __syncthreads();
    for (int off = 1; off < 256; off <<= 1) {
        int w = (tid >= off && tid < 256) ? scn[tid - off] : 0;
        __syncthreads();
        if (tid < 256) scn[tid] += w;
        __syncthreads();
    }
    if (tid < 256) {
        int excl = scn[tid] - orig;
        bump[tid] = g0 + excl;
        int node = b * BSZ + tid;
        if (node < N) {
            float dv = rsqrtf((float)(orig + 1));
            dinv[node] = dv;
            xd[node] = x[node] * dv;
            e_start[node] = g0 + excl;
        }
    }
    if (b == NB2 - 1 && tid == 0) e_start[N] = g1;
    __syncthreads();
    for (int i = tid; i < cnt; i += 512) {
        unsigned pk = fits ? sdata[i] : bkt_data[g0 + i];
        int p = atomicAdd(&bump[pk >> 17], 1);
        csr[p] = pk & 0x1FFFFu;
    }
}

// ---------------- GCN layers: 4 threads per node (feature-quarter each) ----------------
// Intermediate rows: fp8 e4m3 [32] (32B) + f32 per-row scale -> 3.6 MB, fits per-XCD L2.
// Gathers are NONTEMPORAL: zero L1 reuse (random samples of 100k-row tables), and
// bypassing L1 line allocation removes the per-miss tag/victim cost (the r10/r11
// layout-invariant ~42-50us floor).

// o[0..7] += full 32-k matvec: o[f] = sum_k v[k] * W[k][sub*8+f], W row-major in LDS.
__device__ __forceinline__ void mm32_8(const float* __restrict__ sW, const float vr[8],
                                       int sub, int lane, float o[8]) {
    const float4* sW4 = (const float4*)sW;
    int base = lane & ~3;
#pragma unroll
    for (int r = 0; r < 4; r++) {
#pragma unroll
        for (int i = 0; i < 8; i++) {
            float vk = __shfl(vr[i], base | r, 64);
            int k = r * 8 + i;
            float4 w0 = sW4[k * 8 + sub * 2];
            float4 w1 = sW4[k * 8 + sub * 2 + 1];
            o[0] += vk * w0.x; o[1] += vk * w0.y; o[2] += vk * w0.z; o[3] += vk * w0.w;
            o[4] += vk * w1.x; o[5] += vk * w1.y; o[6] += vk * w1.z; o[7] += vk * w1.w;
        }
    }
}

// quantize o[8] (pre-scaled) to fp8 quarter + store; rm reduced across quad.
__device__ __forceinline__ void store_f8(unsigned char* __restrict__ u8, float* __restrict__ uscale,
                                         int d, int sub, const float o[8]) {
    float am = 0.f;
#pragma unroll
    for (int i = 0; i < 8; i++) am = fmaxf(am, fabsf(o[i]));
    am = fmaxf(am, __shfl_xor(am, 1, 64));
    am = fmaxf(am, __shfl_xor(am, 2, 64));
    float rm = fmaxf(am, 1e-20f);
    float sc = 128.f / rm;
    unsigned w0 = 0, w1 = 0;
    w0 = __builtin_amdgcn_cvt_pk_fp8_f32(o[0] * sc, o[1] * sc, w0, false);
    w0 = __builtin_amdgcn_cvt_pk_fp8_f32(o[2] * sc, o[3] * sc, w0, true);
    w1 = __builtin_amdgcn_cvt_pk_fp8_f32(o[4] * sc, o[5] * sc, w1, false);
    w1 = __builtin_amdgcn_cvt_pk_fp8_f32(o[6] * sc, o[7] * sc, w1, true);
    uvec2 st; st.x = w0; st.y = w1;
    ((uvec2*)u8)[(size_t)d * 4 + sub] = st;
    if (sub == 0) uscale[d] = rm * (1.f / 128.f);
}

// stage this block's contiguous csr slice into LDS (NT load); returns fits flag.
__device__ __forceinline__ bool stage_csr(const unsigned* __restrict__ csr,
                                          const int* __restrict__ e_start,
                                          int d0, int dEnd, int* sidx, int& E0) {
    E0 = e_start[d0];
    int E1 = e_start[dEnd];
    int m = E1 - E0;
    bool fits = (m <= SLDS);
    if (fits) {
        for (int i = threadIdx.x; i < m; i += 256)
            sidx[i] = (int)__builtin_nontemporal_load(&csr[E0 + i]);
    }
    __syncthreads();
    return fits;
}

// agg1: rank-1 gather (scalar xd, NT), strided over 4 subs + quad-reduce; fused MLP.
__global__ void __launch_bounds__(256) agg1_kernel(
                            const float* __restrict__ xd, const int* __restrict__ e_start,
                            const unsigned* __restrict__ csr, const float* __restrict__ dinv,
                            const float* __restrict__ W1, const float* __restrict__ b1,
                            const float* __restrict__ W2,
                            unsigned char* __restrict__ u8o, float* __restrict__ uso, int n) {
    __shared__ float sW2[1024];
    __shared__ float sW1[32], sb1[32];
    __shared__ int sidx[SLDS];
    for (int i = threadIdx.x; i < 1024; i += 256) sW2[i] = W2[i];
    if (threadIdx.x < 32) { sW1[threadIdx.x] = W1[threadIdx.x]; sb1[threadIdx.x] = b1[threadIdx.x]; }
    int d0 = blockIdx.x * 64;
    int dEnd = min(d0 + 64, n);
    int E0;
    bool fits = stage_csr(csr, e_start, d0, dEnd, sidx, E0);
    int d = d0 + (threadIdx.x >> 2), sub = threadIdx.x & 3;
    int lane = threadIdx.x & 63;
    if (d >= n) return;
    int e0 = e_start[d];
    int cnt = e_start[d + 1] - e0;
    int l0 = e0 - E0;
    float s = 0.f;
    int j = sub;
    if (fits) {
        for (; j < cnt; j += 4) s += __builtin_nontemporal_load(&xd[sidx[l0 + j]]);
    } else {
        for (; j < cnt; j += 4) s += __builtin_nontemporal_load(&xd[(int)csr[e0 + j]]);
    }
    s += __shfl_xor(s, 1, 64);
    s += __shfl_xor(s, 2, 64);
    float dv = dinv[d];
    float tt = dv * (s + xd[d]);
    float vr[8];
#pragma unroll
    for (int i = 0; i < 8; i++) vr[i] = fmaxf(tt * sW1[sub * 8 + i] + sb1[sub * 8 + i], 0.f);
    float o[8];
#pragma unroll
    for (int i = 0; i < 8; i++) o[i] = 0.f;
    mm32_8(sW2, vr, sub, lane, o);
#pragma unroll
    for (int i = 0; i < 8; i++) o[i] *= dv;
    store_f8(u8o, uso, d, sub, o);
}

// shared fp8 gather with LDS-staged indices; all random loads nontemporal.
__device__ __forceinline__ void gather_f8(const unsigned char* __restrict__ u8,
                                          const float* __restrict__ uscale,
                                          const int* __restrict__ sidx, bool fits,
                                          const unsigned* __restrict__ csr,
                                          int e0, int l0, int cnt, int d, int sub, float acc[8]) {
#pragma unroll
    for (int i = 0; i < 8; i++) acc[i] = 0.f;
    const uvec2* rows = (const uvec2*)u8;
    int j = 0;
    if (fits) {
        for (; j + 4 <= cnt; j += 4) {
            int i0 = sidx[l0 + j],     i1 = sidx[l0 + j + 1];
            int i2 = sidx[l0 + j + 2], i3 = sidx[l0 + j + 3];
            float r0 = __builtin_nontemporal_load(&uscale[i0]);
            float r1 = __builtin_nontemporal_load(&uscale[i1]);
            float r2 = __builtin_nontemporal_load(&uscale[i2]);
            float r3 = __builtin_nontemporal_load(&uscale[i3]);
            uvec2 q0 = __builtin_nontemporal_load(rows + (size_t)i0 * 4 + sub);
            uvec2 q1 = __builtin_nontemporal_load(rows + (size_t)i1 * 4 + sub);
            uvec2 q2 = __builtin_nontemporal_load(rows + (size_t)i2 * 4 + sub);
            uvec2 q3 = __builtin_nontemporal_load(rows + (size_t)i3 * 4 + sub);
            f8acc(q0, r0, acc); f8acc(q1, r1, acc); f8acc(q2, r2, acc); f8acc(q3, r3, acc);
        }
        for (; j < cnt; j++) {
            int i0 = sidx[l0 + j];
            float r0 = __builtin_nontemporal_load(&uscale[i0]);
            uvec2 q0 = __builtin_nontemporal_load(rows + (size_t)i0 * 4 + sub);
            f8acc(q0, r0, acc);
        }
    } else {
        for (; j + 4 <= cnt; j += 4) {
            int i0 = (int)csr[e0 + j],     i1 = (int)csr[e0 + j + 1];
            int i2 = (int)csr[e0 + j + 2], i3 = (int)csr[e0 + j + 3];
            float r0 = __builtin_nontemporal_load(&uscale[i0]);
            float r1 = __builtin_nontemporal_load(&uscale[i1]);
            float r2 = __builtin_nontemporal_load(&uscale[i2]);
            float r3 = __builtin_nontemporal_load(&uscale[i3]);
            uvec2 q0 = __builtin_nontemporal_load(rows + (size_t)i0 * 4 + sub);
            uvec2 q1 = __builtin_nontemporal_load(rows + (size_t)i1 * 4 + sub);
            uvec2 q2 = __builtin_nontemporal_load(rows + (size_t)i2 * 4 + sub);
            uvec2 q3 = __builtin_nontemporal_load(rows + (size_t)i3 * 4 + sub);
            f8acc(q0, r0, acc); f8acc(q1, r1, acc); f8acc(q2, r2, acc); f8acc(q3, r3, acc);
        }
        for (; j < cnt; j++) {
            int i0 = (int)csr[e0 + j];
            float r0 = __builtin_nontemporal_load(&uscale[i0]);
            uvec2 q0 = __builtin_nontemporal_load(rows + (size_t)i0 * 4 + sub);
            f8acc(q0, r0, acc);
        }
    }
    // self row (plain load: written/rewritten per layer, keep cacheable)
    uvec2 qs = rows[(size_t)d * 4 + sub];
    f8acc(qs, uscale[d], acc);
}

// agg2: gather fp8 rows; v=relu(dv*acc+b); out = fp8(dv*(v@W)) + scale.
__global__ void __launch_bounds__(256) agg2_kernel(
                            const unsigned char* __restrict__ u8, const float* __restrict__ uscale,
                            const int* __restrict__ e_start, const unsigned* __restrict__ csr,
                            const float* __restrict__ dinv, const float* __restrict__ bias,
                            const float* __restrict__ W,
                            unsigned char* __restrict__ o8, float* __restrict__ oscale, int n) {
    __shared__ float sW[1024];
    __shared__ float sb[32];
    __shared__ int sidx[SLDS];
    for (int i = threadIdx.x; i < 1024; i += 256) sW[i] = W[i];
    if (threadIdx.x < 32) sb[threadIdx.x] = bias[threadIdx.x];
    int d0 = blockIdx.x * 64;
    int dEnd = min(d0 + 64, n);
    int E0;
    bool fits = stage_csr(csr, e_start, d0, dEnd, sidx, E0);
    int d = d0 + (threadIdx.x >> 2), sub = threadIdx.x & 3;
    int lane = threadIdx.x & 63;
    if (d >= n) return;
    int e0 = e_start[d];
    int cnt = e_start[d + 1] - e0;
    float acc[8];
    gather_f8(u8, uscale, sidx, fits, csr, e0, e0 - E0, cnt, d, sub, acc);
    float dv = dinv[d];
    float vr[8];
#pragma unroll
    for (int i = 0; i < 8; i++) vr[i] = fmaxf(dv * acc[i] + sb[sub * 8 + i], 0.f);
    float o[8];
#pragma unroll
    for (int i = 0; i < 8; i++) o[i] = 0.f;
    mm32_8(sW, vr, sub, lane, o);
#pragma unroll
    for (int i = 0; i < 8; i++) o[i] *= dv;
    store_f8(o8, oscale, d, sub, o);
}

// agg3: v=relu(dv*acc+b3) -> hb (bf16, NT); theta head (NT store).
__global__ void __launch_bounds__(256) agg3_kernel(
                            const unsigned char* __restrict__ u8, const float* __restrict__ uscale,
                            const int* __restrict__ e_start, const unsigned* __restrict__ csr,
                            const float* __restrict__ dinv, const float* __restrict__ bias,
                            const float* __restrict__ Wt1, const float* __restrict__ bt1,
                            const float* __restrict__ Wt2, const float* __restrict__ bt2,
                            unsigned short* __restrict__ hb, float* __restrict__ theta, int n) {
    __shared__ float sW[1024];
    __shared__ float sb[32], sbt[32], sw2[32];
    __shared__ int sidx[SLDS];
    for (int i = threadIdx.x; i < 1024; i += 256) sW[i] = Wt1[i];
    if (threadIdx.x < 32) {
        sb[threadIdx.x] = bias[threadIdx.x];
        sbt[threadIdx.x] = bt1[threadIdx.x];
        sw2[threadIdx.x] = Wt2[threadIdx.x];
    }
    int d0 = blockIdx.x * 64;
    int dEnd = min(d0 + 64, n);
    int E0;
    bool fits = stage_csr(csr, e_start, d0, dEnd, sidx, E0);
    int d = d0 + (threadIdx.x >> 2), sub = threadIdx.x & 3;
    int lane = threadIdx.x & 63;
    if (d >= n) return;
    int e0 = e_start[d];
    int cnt = e_start[d + 1] - e0;
    float acc[8];
    gather_f8(u8, uscale, sidx, fits, csr, e0, e0 - E0, cnt, d, sub, acc);
    float dv = dinv[d];
    float vr[8];
#pragma unroll
    for (int i = 0; i < 8; i++) vr[i] = fmaxf(dv * acc[i] + sb[sub * 8 + i], 0.f);
    uvec4 st;
    st.x = bfpack(vr[0], vr[1]);
    st.y = bfpack(vr[2], vr[3]);
    st.z = bfpack(vr[4], vr[5]);
    st.w = bfpack(vr[6], vr[7]);
    __builtin_nontemporal_store(st, (uvec4*)hb + (size_t)d * 4 + sub);
    float o[8];
#pragma unroll
    for (int i = 0; i < 8; i++) o[i] = 0.f;
    mm32_8(sW, vr, sub, lane, o);
    float tl = 0.f;
#pragma unroll
    for (int i = 0; i < 8; i++)
        tl += fmaxf(o[i] + sbt[sub * 8 + i], 0.f) * sw2[sub * 8 + i];
    tl += __shfl_xor(tl, 1, 64);
    tl += __shfl_xor(tl, 2, 64);
    if (sub == 0) __builtin_nontemporal_store(PI_F / (1.f + __expf(-(tl + bt2[0]))), theta + d);
}

// ---------------- pooled head: block-per-graph reduce ----------------

__global__ void __launch_bounds__(512) bg_kernel(
                          const unsigned short* __restrict__ hb, const int* __restrict__ gstart,
                          const float* __restrict__ Wg1, const float* __restrict__ bg1v,
                          const float* __restrict__ Wg2, const float* __restrict__ bg2v,
                          float* __restrict__ out, int G) {
    __shared__ float sW[1024];
    __shared__ float part[8][32];
    for (int i = threadIdx.x; i < 1024; i += 512) sW[i] = Wg1[i];
    int g = blockIdx.x;
    int s = gstart[g], e = gstart[g + 1];
    int w = threadIdx.x >> 6;
    int lane = threadIdx.x & 63;
    int f = lane & 31, h = lane >> 5;
    float a = 0.f;
    for (int i = s + (w << 1) + h; i < e; i += 16)
        a += __uint_as_float((unsigned)hb[((size_t)i << 5) + f] << 16);
    a += __shfl_xor(a, 32, 64);
    if (h == 0) part[w][f] = a;
    __syncthreads();
    if (w == 0) {
        float hv = 0.f;
#pragma unroll
        for (int p = 0; p < 8; p++) hv += part[p][f];
        hv /= fmaxf((float)(e - s), 1.f);
        int base = lane & 32;
        float acc = bg1v[f];
#pragma unroll
        for (int k = 0; k < 32; k++) acc += __shfl(hv, base | k, 64) * sW[k * 32 + f];
        acc = fmaxf(acc, 0.f);
        float p0 = acc * Wg2[f * 2 + 0];
        float p1 = acc * Wg2[f * 2 + 1];
#pragma unroll
        for (int m = 1; m < 32; m <<= 1) {
            p0 += __shfl_xor(p0, m, 64);
            p1 += __shfl_xor(p1, m, 64);
        }
        if (f == 0) {
            out[g * 2 + 0] = 2.f * PI_F / (1.f + __expf(-(p0 + bg2v[0])));
            out[g * 2 + 1] = 2.f * PI_F / (1.f + __expf(-(p1 + bg2v[1])));
        }
    }
}

// ---------------- launch ----------------

extern "C" void kernel_launch(void* const* d_in, const int* in_sizes, int n_in,
                              void* d_out, int out_size, void* d_ws, size_t ws_size,
                              hipStream_t stream) {
    const float* x   = (const float*)d_in[0];
    const int*   ei  = (const int*)d_in[1];
    const int* batch = (const int*)d_in[2];
    const float* W1  = (const float*)d_in[3];
    const float* b1  = (const float*)d_in[4];
    const float* W2  = (const float*)d_in[5];
    const float* b2  = (const float*)d_in[6];
    const float* W3  = (const float*)d_in[7];
    const float* b3  = (const float*)d_in[8];
    const float* Wt1 = (const float*)d_in[9];
    const float* bt1 = (const float*)d_in[10];
    const float* Wt2 = (const float*)d_in[11];
    const float* bt2 = (const float*)d_in[12];
    const float* Wg1 = (const float*)d_in[13];
    const float* bg1 = (const float*)d_in[14];
    const float* Wg2 = (const float*)d_in[15];
    const float* bg2 = (const float*)d_in[16];

    const int N = in_sizes[0];
    const int E = in_sizes[1] / 2;
    const int G = 128;
    const int* src = ei;
    const int* dst = ei + E;
    float* theta_out = (float*)d_out;
    float* bg_out = (float*)d_out + N;

    const int NB2 = (N + BSZ - 1) >> BSH;
    const int CHUNK = (E + NBLK - 1) / NBLK;

    char* w = (char*)d_ws;
    auto alloc = [&](size_t bytes) -> char* { char* p = w; w += align256(bytes); return p; };
    int*      C        = (int*)alloc((size_t)NBLK * NB2 * 4);
    int*      colsum   = (int*)alloc((size_t)NB2 * 4);
    int*      bbase    = (int*)alloc((size_t)(NB2 + 1) * 4);
    unsigned* bkt_data = (unsigned*)alloc((size_t)E * 4);
    unsigned* csr      = (unsigned*)alloc((size_t)E * 4);
    int*      e_start  = (int*)alloc((size_t)(N + 1) * 4);
    float*    dinv     = (float*)alloc((size_t)N * 4);
    float*    xd       = (float*)alloc((size_t)N * 4);
    unsigned char* u2  = (unsigned char*)alloc((size_t)N * 32);
    float*    us2      = (float*)alloc((size_t)N * 4);
    unsigned char* u3  = (unsigned char*)alloc((size_t)N * 32);
    float*    us3      = (float*)alloc((size_t)N * 4);
    unsigned short* hb = (unsigned short*)alloc((size_t)N * 64);
    int*      gstart   = (int*)alloc((size_t)(G + 1) * 4);

    size_t ldsB = (size_t)NB2 * 4;
    count_kernel<<<NBLK, 1024, ldsB, stream>>>(dst, C, E, CHUNK, NB2);
    scan_blocks_kernel<<<NB2, 256, 0, stream>>>(C, colsum, NB2, batch, gstart, N, G);
    scan_totals_kernel<<<1, 256, 0, stream>>>(colsum, bbase, NB2, E);
    scatter_kernel<<<NBLK, 1024, ldsB, stream>>>(src, dst, C, bbase, bkt_data, E, CHUNK, NB2);
    csr_build_kernel<<<NB2, 512, 0, stream>>>(bkt_data, bbase, x, csr, e_start, dinv, xd, N, NB2);

    unsigned gridQ = (unsigned)(((size_t)N * 4 + 255) / 256);   // 4 threads per node

    agg1_kernel<<<gridQ, 256, 0, stream>>>(xd, e_start, csr, dinv, W1, b1, W2, u2, us2, N);
    agg2_kernel<<<gridQ, 256, 0, stream>>>(u2, us2, e_start, csr, dinv, b2, W3, u3, us3, N);
    agg3_kernel<<<gridQ, 256, 0, stream>>>(u3, us3, e_start, csr, dinv, b3,
                                           Wt1, bt1, Wt2, bt2, hb, theta_out, N);

    bg_kernel<<<G, 512, 0, stream>>>(hb, gstart, Wg1, bg1, Wg2, bg2, bg_out, G);
}

// Round 13
// 286.047 us; speedup vs baseline: 1.3162x; 1.3162x over previous
//
#include <hip/hip_runtime.h>
#include <hip/hip_bf16.h>

#define PI_F 3.14159265358979323846f
#define NBLK 128     // chunk count for count/scatter passes (scan width)
#define BSH 8        // coarse bucket = 256 dst nodes
#define BSZ 256      // nodes per bucket
#define SCAP 10240   // LDS edge staging capacity (mean 8192, +22 sigma)
#define SLDS 3072    // per-block csr staging for agg kernels (64 nodes, mean 2048, +22 sigma)

static inline size_t align256(size_t x) { return (x + 255) & ~size_t(255); }

typedef float v2f __attribute__((ext_vector_type(2)));
typedef unsigned uvec2 __attribute__((ext_vector_type(2)));
typedef unsigned uvec4 __attribute__((ext_vector_type(4)));   // native vector: NT-store legal

// bf16 helpers (bit tricks; round-to-nearest via +0x8000)
__device__ __forceinline__ unsigned bfpack(float a, float b) {
    unsigned lo = (__float_as_uint(a) + 0x8000u) >> 16;
    unsigned hi = (__float_as_uint(b) + 0x8000u) & 0xFFFF0000u;
    return lo | hi;
}

// pot-scale decode: byte b -> 2^(b-134) = pot/128  (pot = 2^(b-127))
__device__ __forceinline__ float sdec(unsigned char b) {
    return __uint_as_float(((unsigned)b - 7u) << 23);
}

// accumulate one 8B fp8 row-quarter (8 features) scaled by rs into acc[8]
__device__ __forceinline__ void f8acc(uvec2 q, float rs, float acc[8]) {
    v2f l0 = __builtin_amdgcn_cvt_pk_f32_fp8(q.x, false);
    v2f h0 = __builtin_amdgcn_cvt_pk_f32_fp8(q.x, true);
    v2f l1 = __builtin_amdgcn_cvt_pk_f32_fp8(q.y, false);
    v2f h1 = __builtin_amdgcn_cvt_pk_f32_fp8(q.y, true);
    acc[0] += rs * l0.x; acc[1] += rs * l0.y; acc[2] += rs * h0.x; acc[3] += rs * h0.y;
    acc[4] += rs * l1.x; acc[5] += rs * l1.y; acc[6] += rs * h1.x; acc[7] += rs * h1.y;
}

// ---------------- atomic-free bucketed CSR build ----------------

__global__ void __launch_bounds__(1024) count_kernel(
                             const int* __restrict__ dst, int* __restrict__ C,
                             int E, int CHUNK, int NB2) {
    extern __shared__ int hist[];   // NB2 ints
    for (int i = threadIdx.x; i < NB2; i += 1024) hist[i] = 0;
    __syncthreads();
    int s0 = blockIdx.x * CHUNK, s1 = min(s0 + CHUNK, E);
    for (int e = s0 + threadIdx.x; e < s1; e += 1024)
        atomicAdd(&hist[dst[e] >> BSH], 1);
    __syncthreads();
    for (int i = threadIdx.x; i < NB2; i += 1024)
        C[(size_t)blockIdx.x * NB2 + i] = hist[i];
}

// scan of the NBLK per-chunk counts for each bucket (column). 128 threads.
__global__ void __launch_bounds__(128) scan_blocks_kernel(
                                   int* __restrict__ C, int* __restrict__ colsum, int NB2) {
    __shared__ int s[NBLK];
    int k = blockIdx.x;
    int b = threadIdx.x;
    int v = C[(size_t)b * NB2 + k];
    s[b] = v;
    __syncthreads();
    for (int off = 1; off < NBLK; off <<= 1) {
        int w = (b >= off) ? s[b - off] : 0;
        __syncthreads();
        s[b] += w;
        __syncthreads();
    }
    C[(size_t)b * NB2 + k] = s[b] - v;   // exclusive
    if (b == NBLK - 1) colsum[k] = s[NBLK - 1];
}

__global__ void scan_totals_kernel(const int* __restrict__ colsum, int* __restrict__ bbase,
                                   int NB2, int E) {
    __shared__ int s[256];
    __shared__ int running;
    if (threadIdx.x == 0) running = 0;
    __syncthreads();
    for (int base = 0; base < NB2; base += 256) {
        int i = base + threadIdx.x;
        int v = (i < NB2) ? colsum[i] : 0;
        s[threadIdx.x] = v;
        __syncthreads();
        for (int off = 1; off < 256; off <<= 1) {
            int w = (threadIdx.x >= (unsigned)off) ? s[threadIdx.x - off] : 0;
            __syncthreads();
            s[threadIdx.x] += w;
            __syncthreads();
        }
        if (i < NB2) bbase[i] = running + s[threadIdx.x] - v;
        __syncthreads();
        if (threadIdx.x == 255) running += s[255];
        __syncthreads();
    }
    if (threadIdx.x == 0) bbase[NB2] = E;
}

__global__ void __launch_bounds__(1024) scatter_kernel(
                               const int* __restrict__ src, const int* __restrict__ dst,
                               const int* __restrict__ C, const int* __restrict__ bbase,
                               unsigned* __restrict__ bkt_data, int E, int CHUNK, int NB2) {
    extern __shared__ int ofs[];   // NB2 ints
    for (int i = threadIdx.x; i < NB2; i += 1024)
        ofs[i] = bbase[i] + C[(size_t)blockIdx.x * NB2 + i];
    __syncthreads();
    int s0 = blockIdx.x * CHUNK, s1 = min(s0 + CHUNK, E);
    for (int e = s0 + threadIdx.x; e < s1; e += 1024) {
        int d = dst[e];
        int p = atomicAdd(&ofs[d >> BSH], 1);   // LDS atomic only
        bkt_data[p] = ((unsigned)(d & (BSZ - 1)) << 17) | (unsigned)src[e];
    }
}

// csr build + fused graph-boundary index (grid covers all N via b*256+tid).
__global__ void __launch_bounds__(512) csr_build_kernel(
                                 const unsigned* __restrict__ bkt_data, const int* __restrict__ bbase,
                                 const float* __restrict__ x,
                                 unsigned* __restrict__ csr, int* __restrict__ e_start,
                                 float* __restrict__ dinv, float* __restrict__ xd,
                                 const int* __restrict__ batch, int* __restrict__ gstart,
                                 int N, int NB2, int G) {
    __shared__ unsigned sdata[SCAP];
    __shared__ int hist[256];
    __shared__ int scn[256];
    __shared__ int bump[256];
    int tid = threadIdx.x;
    int b = blockIdx.x;
    int g0 = bbase[b], g1 = bbase[b + 1];
    int cnt = g1 - g0;
    bool fits = (cnt <= SCAP);
    if (tid < 256) hist[tid] = 0;
    __syncthreads();
    for (int i = tid; i < cnt; i += 512) {
        unsigned pk = bkt_data[g0 + i];
        if (fits) sdata[i] = pk;
        atomicAdd(&hist[pk >> 17], 1);
    }
    __syncthreads();
    int orig = (tid < 256) ? hist[tid] : 0;
    if (tid < 256) scn[tid] = orig;
    __syncthreads();
    for (int off = 1; off < 256; off <<= 1) {
        int w = (tid >= off && tid < 256) ? scn[tid - off] : 0;
        __syncthreads();
        if (tid < 256) scn[tid] += w;
        __syncthreads();
    }
    if (tid < 256) {
        int excl = scn[tid] - orig;
        bump[tid] = g0 + excl;
        int node = b * BSZ + tid;
        if (node < N) {
            float dv = rsqrtf((float)(orig + 1));
            dinv[node] = dv;
            xd[node] = x[node] * dv;
            e_start[node] = g0 + excl;
            // fused gb: graph boundary detection
            int g = batch[node];
            if (node == 0) {
                for (int gg = 0; gg <= g; gg++) gstart[gg] = 0;
            } else {
                int gp = batch[node - 1];
                for (int gg = gp + 1; gg <= g; gg++) gstart[gg] = node;
            }
            if (node == N - 1) {
                for (int gg = g + 1; gg <= G; gg++) gstart[gg] = N;
            }
        }
    }
    if (b == NB2 - 1 && tid == 0) e_start[N] = g1;
    __syncthreads();
    for (int i = tid; i < cnt; i += 512) {
        unsigned pk = fits ? sdata[i] : bkt_data[g0 + i];
        int p = atomicAdd(&bump[pk >> 17], 1);
        csr[p] = pk & 0x1FFFFu;
    }
}

// ---------------- GCN layers: 4 threads per node (feature-quarter each) ----------------
// Intermediate rows: fp8 e4m3 [32] (32B, 3.2MB table, L2-resident) + per-row
// power-of-two scale stored as ONE exponent byte (100KB table -> L1/L2-hot, no
// random line touches). PoT scale is lossless for fp8 (exponent shift only).

// o[0..7] += full 32-k matvec: o[f] = sum_k v[k] * W[k][sub*8+f], W row-major in LDS.
__device__ __forceinline__ void mm32_8(const float* __restrict__ sW, const float vr[8],
                                       int sub, int lane, float o[8]) {
    const float4* sW4 = (const float4*)sW;
    int base = lane & ~3;
#pragma unroll
    for (int r = 0; r < 4; r++) {
#pragma unroll
        for (int i = 0; i < 8; i++) {
            float vk = __shfl(vr[i], base | r, 64);
            int k = r * 8 + i;
            float4 w0 = sW4[k * 8 + sub * 2];
            float4 w1 = sW4[k * 8 + sub * 2 + 1];
            o[0] += vk * w0.x; o[1] += vk * w0.y; o[2] += vk * w0.z; o[3] += vk * w0.w;
            o[4] += vk * w1.x; o[5] += vk * w1.y; o[6] += vk * w1.z; o[7] += vk * w1.w;
        }
    }
}

// quantize o[8] to fp8 quarter + store; pot-scale exponent byte; rm reduced across quad.
__device__ __forceinline__ void store_f8(unsigned char* __restrict__ u8,
                                         unsigned char* __restrict__ uscale,
                                         int d, int sub, const float o[8]) {
    float am = 0.f;
#pragma unroll
    for (int i = 0; i < 8; i++) am = fmaxf(am, fabsf(o[i]));
    am = fmaxf(am, __shfl_xor(am, 1, 64));
    am = fmaxf(am, __shfl_xor(am, 2, 64));
    float rm = fmaxf(am, 1e-20f);
    unsigned u = __float_as_uint(rm);
    unsigned b = (u >> 23) + ((u & 0x7FFFFFu) ? 1u : 0u);   // pot = 2^(b-127) >= rm
    float sc = __uint_as_float((261u - b) << 23);           // 128/pot
    unsigned w0 = 0, w1 = 0;
    w0 = __builtin_amdgcn_cvt_pk_fp8_f32(o[0] * sc, o[1] * sc, w0, false);
    w0 = __builtin_amdgcn_cvt_pk_fp8_f32(o[2] * sc, o[3] * sc, w0, true);
    w1 = __builtin_amdgcn_cvt_pk_fp8_f32(o[4] * sc, o[5] * sc, w1, false);
    w1 = __builtin_amdgcn_cvt_pk_fp8_f32(o[6] * sc, o[7] * sc, w1, true);
    uvec2 st; st.x = w0; st.y = w1;
    ((uvec2*)u8)[(size_t)d * 4 + sub] = st;
    if (sub == 0) uscale[d] = (unsigned char)b;
}

// stage this block's contiguous csr slice into LDS (NT load); returns fits flag.
__device__ __forceinline__ bool stage_csr(const unsigned* __restrict__ csr,
                                          const int* __restrict__ e_start,
                                          int d0, int dEnd, int* sidx, int& E0) {
    E0 = e_start[d0];
    int E1 = e_start[dEnd];
    int m = E1 - E0;
    bool fits = (m <= SLDS);
    if (fits) {
        for (int i = threadIdx.x; i < m; i += 256)
            sidx[i] = (int)__builtin_nontemporal_load(&csr[E0 + i]);
    }
    __syncthreads();
    return fits;
}

// agg1: rank-1 gather (scalar xd), strided over 4 subs + quad-reduce; then fused MLP.
__global__ void __launch_bounds__(256) agg1_kernel(
                            const float* __restrict__ xd, const int* __restrict__ e_start,
                            const unsigned* __restrict__ csr, const float* __restrict__ dinv,
                            const float* __restrict__ W1, const float* __restrict__ b1,
                            const float* __restrict__ W2,
                            unsigned char* __restrict__ u8o, unsigned char* __restrict__ uso, int n) {
    __shared__ float sW2[1024];
    __shared__ float sW1[32], sb1[32];
    __shared__ int sidx[SLDS];
    for (int i = threadIdx.x; i < 1024; i += 256) sW2[i] = W2[i];
    if (threadIdx.x < 32) { sW1[threadIdx.x] = W1[threadIdx.x]; sb1[threadIdx.x] = b1[threadIdx.x]; }
    int d0 = blockIdx.x * 64;
    int dEnd = min(d0 + 64, n);
    int E0;
    bool fits = stage_csr(csr, e_start, d0, dEnd, sidx, E0);
    int d = d0 + (threadIdx.x >> 2), sub = threadIdx.x & 3;
    int lane = threadIdx.x & 63;
    if (d >= n) return;
    int e0 = e_start[d];
    int cnt = e_start[d + 1] - e0;
    int l0 = e0 - E0;
    float s = 0.f;
    int j = sub;
    if (fits) {
        for (; j < cnt; j += 4) s += xd[sidx[l0 + j]];
    } else {
        for (; j < cnt; j += 4) s += xd[(int)csr[e0 + j]];
    }
    s += __shfl_xor(s, 1, 64);
    s += __shfl_xor(s, 2, 64);
    float dv = dinv[d];
    float tt = dv * (s + xd[d]);
    float vr[8];
#pragma unroll
    for (int i = 0; i < 8; i++) vr[i] = fmaxf(tt * sW1[sub * 8 + i] + sb1[sub * 8 + i], 0.f);
    float o[8];
#pragma unroll
    for (int i = 0; i < 8; i++) o[i] = 0.f;
    mm32_8(sW2, vr, sub, lane, o);
#pragma unroll
    for (int i = 0; i < 8; i++) o[i] *= dv;
    store_f8(u8o, uso, d, sub, o);
}

// shared fp8 gather with LDS-staged indices; plain (cacheable) loads — the row
// table is L2-resident and the scale table is L1-hot.
__device__ __forceinline__ void gather_f8(const unsigned char* __restrict__ u8,
                                          const unsigned char* __restrict__ uscale,
                                          const int* __restrict__ sidx, bool fits,
                                          const unsigned* __restrict__ csr,
                                          int e0, int l0, int cnt, int d, int sub, float acc[8]) {
#pragma unroll
    for (int i = 0; i < 8; i++) acc[i] = 0.f;
    const uvec2* rows = (const uvec2*)u8;
    int j = 0;
    if (fits) {
        for (; j + 4 <= cnt; j += 4) {
            int i0 = sidx[l0 + j],     i1 = sidx[l0 + j + 1];
            int i2 = sidx[l0 + j + 2], i3 = sidx[l0 + j + 3];
            float r0 = sdec(uscale[i0]), r1 = sdec(uscale[i1]);
            float r2 = sdec(uscale[i2]), r3 = sdec(uscale[i3]);
            uvec2 q0 = rows[(size_t)i0 * 4 + sub];
            uvec2 q1 = rows[(size_t)i1 * 4 + sub];
            uvec2 q2 = rows[(size_t)i2 * 4 + sub];
            uvec2 q3 = rows[(size_t)i3 * 4 + sub];
            f8acc(q0, r0, acc); f8acc(q1, r1, acc); f8acc(q2, r2, acc); f8acc(q3, r3, acc);
        }
        for (; j < cnt; j++) {
            int i0 = sidx[l0 + j];
            f8acc(rows[(size_t)i0 * 4 + sub], sdec(uscale[i0]), acc);
        }
    } else {
        for (; j + 4 <= cnt; j += 4) {
            int i0 = (int)csr[e0 + j],     i1 = (int)csr[e0 + j + 1];
            int i2 = (int)csr[e0 + j + 2], i3 = (int)csr[e0 + j + 3];
            float r0 = sdec(uscale[i0]), r1 = sdec(uscale[i1]);
            float r2 = sdec(uscale[i2]), r3 = sdec(uscale[i3]);
            uvec2 q0 = rows[(size_t)i0 * 4 + sub];
            uvec2 q1 = rows[(size_t)i1 * 4 + sub];
            uvec2 q2 = rows[(size_t)i2 * 4 + sub];
            uvec2 q3 = rows[(size_t)i3 * 4 + sub];
            f8acc(q0, r0, acc); f8acc(q1, r1, acc); f8acc(q2, r2, acc); f8acc(q3, r3, acc);
        }
        for (; j < cnt; j++) {
            int i0 = (int)csr[e0 + j];
            f8acc(rows[(size_t)i0 * 4 + sub], sdec(uscale[i0]), acc);
        }
    }
    // self row
    uvec2 qs = rows[(size_t)d * 4 + sub];
    f8acc(qs, sdec(uscale[d]), acc);
}

// agg2: gather fp8 rows; v=relu(dv*acc+b); out = fp8(dv*(v@W)) + pot-scale byte.
__global__ void __launch_bounds__(256) agg2_kernel(
                            const unsigned char* __restrict__ u8, const unsigned char* __restrict__ uscale,
                            const int* __restrict__ e_start, const unsigned* __restrict__ csr,
                            const float* __restrict__ dinv, const float* __restrict__ bias,
                            const float* __restrict__ W,
                            unsigned char* __restrict__ o8, unsigned char* __restrict__ oscale, int n) {
    __shared__ float sW[1024];
    __shared__ float sb[32];
    __shared__ int sidx[SLDS];
    for (int i = threadIdx.x; i < 1024; i += 256) sW[i] = W[i];
    if (threadIdx.x < 32) sb[threadIdx.x] = bias[threadIdx.x];
    int d0 = blockIdx.x * 64;
    int dEnd = min(d0 + 64, n);
    int E0;
    bool fits = stage_csr(csr, e_start, d0, dEnd, sidx, E0);
    int d = d0 + (threadIdx.x >> 2), sub = threadIdx.x & 3;
    int lane = threadIdx.x & 63;
    if (d >= n) return;
    int e0 = e_start[d];
    int cnt = e_start[d + 1] - e0;
    float acc[8];
    gather_f8(u8, uscale, sidx, fits, csr, e0, e0 - E0, cnt, d, sub, acc);
    float dv = dinv[d];
    float vr[8];
#pragma unroll
    for (int i = 0; i < 8; i++) vr[i] = fmaxf(dv * acc[i] + sb[sub * 8 + i], 0.f);
    float o[8];
#pragma unroll
    for (int i = 0; i < 8; i++) o[i] = 0.f;
    mm32_8(sW, vr, sub, lane, o);
#pragma unroll
    for (int i = 0; i < 8; i++) o[i] *= dv;
    store_f8(o8, oscale, d, sub, o);
}

// agg3: v=relu(dv*acc+b3) -> hb (bf16, NT); theta head (NT store).
__global__ void __launch_bounds__(256) agg3_kernel(
                            const unsigned char* __restrict__ u8, const unsigned char* __restrict__ uscale,
                            const int* __restrict__ e_start, const unsigned* __restrict__ csr,
                            const float* __restrict__ dinv, const float* __restrict__ bias,
                            const float* __restrict__ Wt1, const float* __restrict__ bt1,
                            const float* __restrict__ Wt2, const float* __restrict__ bt2,
                            unsigned short* __restrict__ hb, float* __restrict__ theta, int n) {
    __shared__ float sW[1024];
    __shared__ float sb[32], sbt[32], sw2[32];
    __shared__ int sidx[SLDS];
    for (int i = threadIdx.x; i < 1024; i += 256) sW[i] = Wt1[i];
    if (threadIdx.x < 32) {
        sb[threadIdx.x] = bias[threadIdx.x];
        sbt[threadIdx.x] = bt1[threadIdx.x];
        sw2[threadIdx.x] = Wt2[threadIdx.x];
    }
    int d0 = blockIdx.x * 64;
    int dEnd = min(d0 + 64, n);
    int E0;
    bool fits = stage_csr(csr, e_start, d0, dEnd, sidx, E0);
    int d = d0 + (threadIdx.x >> 2), sub = threadIdx.x & 3;
    int lane = threadIdx.x & 63;
    if (d >= n) return;
    int e0 = e_start[d];
    int cnt = e_start[d + 1] - e0;
    float acc[8];
    gather_f8(u8, uscale, sidx, fits, csr, e0, e0 - E0, cnt, d, sub, acc);
    float dv = dinv[d];
    float vr[8];
#pragma unroll
    for (int i = 0; i < 8; i++) vr[i] = fmaxf(dv * acc[i] + sb[sub * 8 + i], 0.f);
    uvec4 st;
    st.x = bfpack(vr[0], vr[1]);
    st.y = bfpack(vr[2], vr[3]);
    st.z = bfpack(vr[4], vr[5]);
    st.w = bfpack(vr[6], vr[7]);
    __builtin_nontemporal_store(st, (uvec4*)hb + (size_t)d * 4 + sub);
    float o[8];
#pragma unroll
    for (int i = 0; i < 8; i++) o[i] = 0.f;
    mm32_8(sW, vr, sub, lane, o);
    float tl = 0.f;
#pragma unroll
    for (int i = 0; i < 8; i++)
        tl += fmaxf(o[i] + sbt[sub * 8 + i], 0.f) * sw2[sub * 8 + i];
    tl += __shfl_xor(tl, 1, 64);
    tl += __shfl_xor(tl, 2, 64);
    if (sub == 0) __builtin_nontemporal_store(PI_F / (1.f + __expf(-(tl + bt2[0]))), theta + d);
}

// ---------------- pooled head: block-per-graph reduce ----------------

__global__ void __launch_bounds__(512) bg_kernel(
                          const unsigned short* __restrict__ hb, const int* __restrict__ gstart,
                          const float* __restrict__ Wg1, const float* __restrict__ bg1v,
                          const float* __restrict__ Wg2, const float* __restrict__ bg2v,
                          float* __restrict__ out, int G) {
    __shared__ float sW[1024];
    __shared__ float part[8][32];
    for (int i = threadIdx.x; i < 1024; i += 512) sW[i] = Wg1[i];
    int g = blockIdx.x;
    int s = gstart[g], e = gstart[g + 1];
    int w = threadIdx.x >> 6;
    int lane = threadIdx.x & 63;
    int f = lane & 31, h = lane >> 5;
    float a = 0.f;
    for (int i = s + (w << 1) + h; i < e; i += 16)
        a += __uint_as_float((unsigned)hb[((size_t)i << 5) + f] << 16);
    a += __shfl_xor(a, 32, 64);
    if (h == 0) part[w][f] = a;
    __syncthreads();
    if (w == 0) {
        float hv = 0.f;
#pragma unroll
        for (int p = 0; p < 8; p++) hv += part[p][f];
        hv /= fmaxf((float)(e - s), 1.f);
        int base = lane & 32;
        float acc = bg1v[f];
#pragma unroll
        for (int k = 0; k < 32; k++) acc += __shfl(hv, base | k, 64) * sW[k * 32 + f];
        acc = fmaxf(acc, 0.f);
        float p0 = acc * Wg2[f * 2 + 0];
        float p1 = acc * Wg2[f * 2 + 1];
#pragma unroll
        for (int m = 1; m < 32; m <<= 1) {
            p0 += __shfl_xor(p0, m, 64);
            p1 += __shfl_xor(p1, m, 64);
        }
        if (f == 0) {
            out[g * 2 + 0] = 2.f * PI_F / (1.f + __expf(-(p0 + bg2v[0])));
            out[g * 2 + 1] = 2.f * PI_F / (1.f + __expf(-(p1 + bg2v[1])));
        }
    }
}

// ---------------- launch ----------------

extern "C" void kernel_launch(void* const* d_in, const int* in_sizes, int n_in,
                              void* d_out, int out_size, void* d_ws, size_t ws_size,
                              hipStream_t stream) {
    const float* x   = (const float*)d_in[0];
    const int*   ei  = (const int*)d_in[1];
    const int* batch = (const int*)d_in[2];
    const float* W1  = (const float*)d_in[3];
    const float* b1  = (const float*)d_in[4];
    const float* W2  = (const float*)d_in[5];
    const float* b2  = (const float*)d_in[6];
    const float* W3  = (const float*)d_in[7];
    const float* b3  = (const float*)d_in[8];
    const float* Wt1 = (const float*)d_in[9];
    const float* bt1 = (const float*)d_in[10];
    const float* Wt2 = (const float*)d_in[11];
    const float* bt2 = (const float*)d_in[12];
    const float* Wg1 = (const float*)d_in[13];
    const float* bg1 = (const float*)d_in[14];
    const float* Wg2 = (const float*)d_in[15];
    const float* bg2 = (const float*)d_in[16];

    const int N = in_sizes[0];
    const int E = in_sizes[1] / 2;
    const int G = 128;
    const int* src = ei;
    const int* dst = ei + E;
    float* theta_out = (float*)d_out;
    float* bg_out = (float*)d_out + N;

    const int NB2 = (N + BSZ - 1) >> BSH;
    const int CHUNK = (E + NBLK - 1) / NBLK;

    char* w = (char*)d_ws;
    auto alloc = [&](size_t bytes) -> char* { char* p = w; w += align256(bytes); return p; };
    int*      C        = (int*)alloc((size_t)NBLK * NB2 * 4);
    int*      colsum   = (int*)alloc((size_t)NB2 * 4);
    int*      bbase    = (int*)alloc((size_t)(NB2 + 1) * 4);
    unsigned* bkt_data = (unsigned*)alloc((size_t)E * 4);
    unsigned* csr      = (unsigned*)alloc((size_t)E * 4);
    int*      e_start  = (int*)alloc((size_t)(N + 1) * 4);
    float*    dinv     = (float*)alloc((size_t)N * 4);
    float*    xd       = (float*)alloc((size_t)N * 4);
    unsigned char* u2  = (unsigned char*)alloc((size_t)N * 32);
    unsigned char* us2 = (unsigned char*)alloc((size_t)N);
    unsigned char* u3  = (unsigned char*)alloc((size_t)N * 32);
    unsigned char* us3 = (unsigned char*)alloc((size_t)N);
    unsigned short* hb = (unsigned short*)alloc((size_t)N * 64);
    int*      gstart   = (int*)alloc((size_t)(G + 1) * 4);

    size_t ldsB = (size_t)NB2 * 4;
    count_kernel<<<NBLK, 1024, ldsB, stream>>>(dst, C, E, CHUNK, NB2);
    scan_blocks_kernel<<<NB2, NBLK, 0, stream>>>(C, colsum, NB2);
    scan_totals_kernel<<<1, 256, 0, stream>>>(colsum, bbase, NB2, E);
    scatter_kernel<<<NBLK, 1024, ldsB, stream>>>(src, dst, C, bbase, bkt_data, E, CHUNK, NB2);
    csr_build_kernel<<<NB2, 512, 0, stream>>>(bkt_data, bbase, x, csr, e_start, dinv, xd,
                                              batch, gstart, N, NB2, G);

    unsigned gridQ = (unsigned)(((size_t)N * 4 + 255) / 256);   // 4 threads per node

    agg1_kernel<<<gridQ, 256, 0, stream>>>(xd, e_start, csr, dinv, W1, b1, W2, u2, us2, N);
    agg2_kernel<<<gridQ, 256, 0, stream>>>(u2, us2, e_start, csr, dinv, b2, W3, u3, us3, N);
    agg3_kernel<<<gridQ, 256, 0, stream>>>(u3, us3, e_start, csr, dinv, b3,
                                           Wt1, bt1, Wt2, bt2, hb, theta_out, N);

    bg_kernel<<<G, 512, 0, stream>>>(hb, gstart, Wg1, bg1, Wg2, bg2, bg_out, G);
}

// Round 14
// 275.184 us; speedup vs baseline: 1.3682x; 1.0395x over previous
//
#include <hip/hip_runtime.h>
#include <hip/hip_bf16.h>

#define PI_F 3.14159265358979323846f
#define NBLK 256     // chunk count for count/scatter passes (scan width)
#define BSH 8        // coarse bucket = 256 dst nodes
#define BSZ 256      // nodes per bucket
#define SCAP 10240   // LDS edge staging capacity (mean 8192, +22 sigma)
#define SLDS 3072    // per-block csr staging for agg kernels (64 nodes, mean 2048, +22 sigma)

static inline size_t align256(size_t x) { return (x + 255) & ~size_t(255); }

typedef float v2f __attribute__((ext_vector_type(2)));
typedef unsigned uvec2 __attribute__((ext_vector_type(2)));
typedef unsigned uvec4 __attribute__((ext_vector_type(4)));   // native vector: NT-store legal

// bf16 helpers (bit tricks; round-to-nearest via +0x8000)
__device__ __forceinline__ unsigned bfpack(float a, float b) {
    unsigned lo = (__float_as_uint(a) + 0x8000u) >> 16;
    unsigned hi = (__float_as_uint(b) + 0x8000u) & 0xFFFF0000u;
    return lo | hi;
}

// pot-scale decode: byte b -> 2^(b-134) = pot/128  (pot = 2^(b-127))
__device__ __forceinline__ float sdec(unsigned char b) {
    return __uint_as_float(((unsigned)b - 7u) << 23);
}

// accumulate one 8B fp8 row-quarter (8 features) scaled by rs into acc[8]
__device__ __forceinline__ void f8acc(uvec2 q, float rs, float acc[8]) {
    v2f l0 = __builtin_amdgcn_cvt_pk_f32_fp8(q.x, false);
    v2f h0 = __builtin_amdgcn_cvt_pk_f32_fp8(q.x, true);
    v2f l1 = __builtin_amdgcn_cvt_pk_f32_fp8(q.y, false);
    v2f h1 = __builtin_amdgcn_cvt_pk_f32_fp8(q.y, true);
    acc[0] += rs * l0.x; acc[1] += rs * l0.y; acc[2] += rs * h0.x; acc[3] += rs * h0.y;
    acc[4] += rs * l1.x; acc[5] += rs * l1.y; acc[6] += rs * h1.x; acc[7] += rs * h1.y;
}

// ---------------- atomic-free bucketed CSR build ----------------

__global__ void __launch_bounds__(1024) count_kernel(
                             const int* __restrict__ dst, int* __restrict__ C,
                             int E, int CHUNK, int NB2) {
    extern __shared__ int hist[];   // NB2 ints
    for (int i = threadIdx.x; i < NB2; i += 1024) hist[i] = 0;
    __syncthreads();
    int s0 = blockIdx.x * CHUNK, s1 = min(s0 + CHUNK, E);
    for (int e = s0 + threadIdx.x; e < s1; e += 1024)
        atomicAdd(&hist[dst[e] >> BSH], 1);
    __syncthreads();
    for (int i = threadIdx.x; i < NB2; i += 1024)
        C[(size_t)blockIdx.x * NB2 + i] = hist[i];
}

// scan of the NBLK per-chunk counts for each bucket (column). 256 threads.
__global__ void __launch_bounds__(256) scan_blocks_kernel(
                                   int* __restrict__ C, int* __restrict__ colsum, int NB2) {
    __shared__ int s[NBLK];
    int k = blockIdx.x;
    int b = threadIdx.x;
    int v = C[(size_t)b * NB2 + k];
    s[b] = v;
    __syncthreads();
    for (int off = 1; off < NBLK; off <<= 1) {
        int w = (b >= off) ? s[b - off] : 0;
        __syncthreads();
        s[b] += w;
        __syncthreads();
    }
    C[(size_t)b * NB2 + k] = s[b] - v;   // exclusive
    if (b == NBLK - 1) colsum[k] = s[NBLK - 1];
}

__global__ void scan_totals_kernel(const int* __restrict__ colsum, int* __restrict__ bbase,
                                   int NB2, int E) {
    __shared__ int s[256];
    __shared__ int running;
    if (threadIdx.x == 0) running = 0;
    __syncthreads();
    for (int base = 0; base < NB2; base += 256) {
        int i = base + threadIdx.x;
        int v = (i < NB2) ? colsum[i] : 0;
        s[threadIdx.x] = v;
        __syncthreads();
        for (int off = 1; off < 256; off <<= 1) {
            int w = (threadIdx.x >= (unsigned)off) ? s[threadIdx.x - off] : 0;
            __syncthreads();
            s[threadIdx.x] += w;
            __syncthreads();
        }
        if (i < NB2) bbase[i] = running + s[threadIdx.x] - v;
        __syncthreads();
        if (threadIdx.x == 255) running += s[255];
        __syncthreads();
    }
    if (threadIdx.x == 0) bbase[NB2] = E;
}

__global__ void __launch_bounds__(1024) scatter_kernel(
                               const int* __restrict__ src, const int* __restrict__ dst,
                               const int* __restrict__ C, const int* __restrict__ bbase,
                               unsigned* __restrict__ bkt_data, int E, int CHUNK, int NB2) {
    extern __shared__ int ofs[];   // NB2 ints
    for (int i = threadIdx.x; i < NB2; i += 1024)
        ofs[i] = bbase[i] + C[(size_t)blockIdx.x * NB2 + i];
    __syncthreads();
    int s0 = blockIdx.x * CHUNK, s1 = min(s0 + CHUNK, E);
    for (int e = s0 + threadIdx.x; e < s1; e += 1024) {
        int d = dst[e];
        int p = atomicAdd(&ofs[d >> BSH], 1);   // LDS atomic only
        bkt_data[p] = ((unsigned)(d & (BSZ - 1)) << 17) | (unsigned)src[e];
    }
}

// csr build + fused graph-boundary index (grid covers all N via b*256+tid).
__global__ void __launch_bounds__(512) csr_build_kernel(
                                 const unsigned* __restrict__ bkt_data, const int* __restrict__ bbase,
                                 const float* __restrict__ x,
                                 unsigned* __restrict__ csr, int* __restrict__ e_start,
                                 float* __restrict__ dinv, float* __restrict__ xd,
                                 const int* __restrict__ batch, int* __restrict__ gstart,
                                 int N, int NB2, int G) {
    __shared__ unsigned sdata[SCAP];
    __shared__ int hist[256];
    __shared__ int scn[256];
    __shared__ int bump[256];
    int tid = threadIdx.x;
    int b = blockIdx.x;
    int g0 = bbase[b], g1 = bbase[b + 1];
    int cnt = g1 - g0;
    bool fits = (cnt <= SCAP);
    if (tid < 256) hist[tid] = 0;
    __syncthreads();
    for (int i = tid; i < cnt; i += 512) {
        unsigned pk = bkt_data[g0 + i];
        if (fits) sdata[i] = pk;
        atomicAdd(&hist[pk >> 17], 1);
    }
    __syncthreads();
    int orig = (tid < 256) ? hist[tid] : 0;
    if (tid < 256) scn[tid] = orig;
    __syncthreads();
    for (int off = 1; off < 256; off <<= 1) {
        int w = (tid >= off && tid < 256) ? scn[tid - off] : 0;
        __syncthreads();
        if (tid < 256) scn[tid] += w;
        __syncthreads();
    }
    if (tid < 256) {
        int excl = scn[tid] - orig;
        bump[tid] = g0 + excl;
        int node = b * BSZ + tid;
        if (node < N) {
            float dv = rsqrtf((float)(orig + 1));
            dinv[node] = dv;
            xd[node] = x[node] * dv;
            e_start[node] = g0 + excl;
            // fused gb: graph boundary detection
            int g = batch[node];
            if (node == 0) {
                for (int gg = 0; gg <= g; gg++) gstart[gg] = 0;
            } else {
                int gp = batch[node - 1];
                for (int gg = gp + 1; gg <= g; gg++) gstart[gg] = node;
            }
            if (node == N - 1) {
                for (int gg = g + 1; gg <= G; gg++) gstart[gg] = N;
            }
        }
    }
    if (b == NB2 - 1 && tid == 0) e_start[N] = g1;
    __syncthreads();
    for (int i = tid; i < cnt; i += 512) {
        unsigned pk = fits ? sdata[i] : bkt_data[g0 + i];
        int p = atomicAdd(&bump[pk >> 17], 1);
        csr[p] = pk & 0x1FFFFu;
    }
}

// ---------------- GCN layers: 4 threads per node (feature-quarter each) ----------------
// Intermediate rows: fp8 e4m3 [32] (32B, 3.2MB table, L2-resident) + per-row
// power-of-two scale stored as ONE exponent byte (100KB table -> L1/L2-hot, no
// random line touches). PoT scale is lossless for fp8 (exponent shift only).

// o[0..7] += full 32-k matvec: o[f] = sum_k v[k] * W[k][sub*8+f], W row-major in LDS.
__device__ __forceinline__ void mm32_8(const float* __restrict__ sW, const float vr[8],
                                       int sub, int lane, float o[8]) {
    const float4* sW4 = (const float4*)sW;
    int base = lane & ~3;
#pragma unroll
    for (int r = 0; r < 4; r++) {
#pragma unroll
        for (int i = 0; i < 8; i++) {
            float vk = __shfl(vr[i], base | r, 64);
            int k = r * 8 + i;
            float4 w0 = sW4[k * 8 + sub * 2];
            float4 w1 = sW4[k * 8 + sub * 2 + 1];
            o[0] += vk * w0.x; o[1] += vk * w0.y; o[2] += vk * w0.z; o[3] += vk * w0.w;
            o[4] += vk * w1.x; o[5] += vk * w1.y; o[6] += vk * w1.z; o[7] += vk * w1.w;
        }
    }
}

// quantize o[8] to fp8 quarter + store; pot-scale exponent byte; rm reduced across quad.
__device__ __forceinline__ void store_f8(unsigned char* __restrict__ u8,
                                         unsigned char* __restrict__ uscale,
                                         int d, int sub, const float o[8]) {
    float am = 0.f;
#pragma unroll
    for (int i = 0; i < 8; i++) am = fmaxf(am, fabsf(o[i]));
    am = fmaxf(am, __shfl_xor(am, 1, 64));
    am = fmaxf(am, __shfl_xor(am, 2, 64));
    float rm = fmaxf(am, 1e-20f);
    unsigned u = __float_as_uint(rm);
    unsigned b = (u >> 23) + ((u & 0x7FFFFFu) ? 1u : 0u);   // pot = 2^(b-127) >= rm
    float sc = __uint_as_float((261u - b) << 23);           // 128/pot
    unsigned w0 = 0, w1 = 0;
    w0 = __builtin_amdgcn_cvt_pk_fp8_f32(o[0] * sc, o[1] * sc, w0, false);
    w0 = __builtin_amdgcn_cvt_pk_fp8_f32(o[2] * sc, o[3] * sc, w0, true);
    w1 = __builtin_amdgcn_cvt_pk_fp8_f32(o[4] * sc, o[5] * sc, w1, false);
    w1 = __builtin_amdgcn_cvt_pk_fp8_f32(o[6] * sc, o[7] * sc, w1, true);
    uvec2 st; st.x = w0; st.y = w1;
    ((uvec2*)u8)[(size_t)d * 4 + sub] = st;
    if (sub == 0) uscale[d] = (unsigned char)b;
}

// stage this block's contiguous csr slice into LDS (NT load); returns fits flag.
__device__ __forceinline__ bool stage_csr(const unsigned* __restrict__ csr,
                                          const int* __restrict__ e_start,
                                          int d0, int dEnd, int* sidx, int& E0) {
    E0 = e_start[d0];
    int E1 = e_start[dEnd];
    int m = E1 - E0;
    bool fits = (m <= SLDS);
    if (fits) {
        for (int i = threadIdx.x; i < m; i += 256)
            sidx[i] = (int)__builtin_nontemporal_load(&csr[E0 + i]);
    }
    __syncthreads();
    return fits;
}

// agg1: rank-1 gather (scalar xd), strided over 4 subs + quad-reduce; then fused MLP.
__global__ void __launch_bounds__(256) agg1_kernel(
                            const float* __restrict__ xd, const int* __restrict__ e_start,
                            const unsigned* __restrict__ csr, const float* __restrict__ dinv,
                            const float* __restrict__ W1, const float* __restrict__ b1,
                            const float* __restrict__ W2,
                            unsigned char* __restrict__ u8o, unsigned char* __restrict__ uso, int n) {
    __shared__ float sW2[1024];
    __shared__ float sW1[32], sb1[32];
    __shared__ int sidx[SLDS];
    for (int i = threadIdx.x; i < 1024; i += 256) sW2[i] = W2[i];
    if (threadIdx.x < 32) { sW1[threadIdx.x] = W1[threadIdx.x]; sb1[threadIdx.x] = b1[threadIdx.x]; }
    int d0 = blockIdx.x * 64;
    int dEnd = min(d0 + 64, n);
    int E0;
    bool fits = stage_csr(csr, e_start, d0, dEnd, sidx, E0);
    int d = d0 + (threadIdx.x >> 2), sub = threadIdx.x & 3;
    int lane = threadIdx.x & 63;
    if (d >= n) return;
    int e0 = e_start[d];
    int cnt = e_start[d + 1] - e0;
    int l0 = e0 - E0;
    float s = 0.f;
    int j = sub;
    if (fits) {
        for (; j < cnt; j += 4) s += xd[sidx[l0 + j]];
    } else {
        for (; j < cnt; j += 4) s += xd[(int)csr[e0 + j]];
    }
    s += __shfl_xor(s, 1, 64);
    s += __shfl_xor(s, 2, 64);
    float dv = dinv[d];
    float tt = dv * (s + xd[d]);
    float vr[8];
#pragma unroll
    for (int i = 0; i < 8; i++) vr[i] = fmaxf(tt * sW1[sub * 8 + i] + sb1[sub * 8 + i], 0.f);
    float o[8];
#pragma unroll
    for (int i = 0; i < 8; i++) o[i] = 0.f;
    mm32_8(sW2, vr, sub, lane, o);
#pragma unroll
    for (int i = 0; i < 8; i++) o[i] *= dv;
    store_f8(u8o, uso, d, sub, o);
}

// shared fp8 gather with LDS-staged indices; plain (cacheable) loads — the row
// table is L2-resident and the scale table is L1-hot.
__device__ __forceinline__ void gather_f8(const unsigned char* __restrict__ u8,
                                          const unsigned char* __restrict__ uscale,
                                          const int* __restrict__ sidx, bool fits,
                                          const unsigned* __restrict__ csr,
                                          int e0, int l0, int cnt, int d, int sub, float acc[8]) {
#pragma unroll
    for (int i = 0; i < 8; i++) acc[i] = 0.f;
    const uvec2* rows = (const uvec2*)u8;
    int j = 0;
    if (fits) {
        for (; j + 4 <= cnt; j += 4) {
            int i0 = sidx[l0 + j],     i1 = sidx[l0 + j + 1];
            int i2 = sidx[l0 + j + 2], i3 = sidx[l0 + j + 3];
            float r0 = sdec(uscale[i0]), r1 = sdec(uscale[i1]);
            float r2 = sdec(uscale[i2]), r3 = sdec(uscale[i3]);
            uvec2 q0 = rows[(size_t)i0 * 4 + sub];
            uvec2 q1 = rows[(size_t)i1 * 4 + sub];
            uvec2 q2 = rows[(size_t)i2 * 4 + sub];
            uvec2 q3 = rows[(size_t)i3 * 4 + sub];
            f8acc(q0, r0, acc); f8acc(q1, r1, acc); f8acc(q2, r2, acc); f8acc(q3, r3, acc);
        }
        for (; j < cnt; j++) {
            int i0 = sidx[l0 + j];
            f8acc(rows[(size_t)i0 * 4 + sub], sdec(uscale[i0]), acc);
        }
    } else {
        for (; j + 4 <= cnt; j += 4) {
            int i0 = (int)csr[e0 + j],     i1 = (int)csr[e0 + j + 1];
            int i2 = (int)csr[e0 + j + 2], i3 = (int)csr[e0 + j + 3];
            float r0 = sdec(uscale[i0]), r1 = sdec(uscale[i1]);
            float r2 = sdec(uscale[i2]), r3 = sdec(uscale[i3]);
            uvec2 q0 = rows[(size_t)i0 * 4 + sub];
            uvec2 q1 = rows[(size_t)i1 * 4 + sub];
            uvec2 q2 = rows[(size_t)i2 * 4 + sub];
            uvec2 q3 = rows[(size_t)i3 * 4 + sub];
            f8acc(q0, r0, acc); f8acc(q1, r1, acc); f8acc(q2, r2, acc); f8acc(q3, r3, acc);
        }
        for (; j < cnt; j++) {
            int i0 = (int)csr[e0 + j];
            f8acc(rows[(size_t)i0 * 4 + sub], sdec(uscale[i0]), acc);
        }
    }
    // self row
    uvec2 qs = rows[(size_t)d * 4 + sub];
    f8acc(qs, sdec(uscale[d]), acc);
}

// agg2: gather fp8 rows; v=relu(dv*acc+b); out = fp8(dv*(v@W)) + pot-scale byte.
__global__ void __launch_bounds__(256) agg2_kernel(
                            const unsigned char* __restrict__ u8, const unsigned char* __restrict__ uscale,
                            const int* __restrict__ e_start, const unsigned* __restrict__ csr,
                            const float* __restrict__ dinv, const float* __restrict__ bias,
                            const float* __restrict__ W,
                            unsigned char* __restrict__ o8, unsigned char* __restrict__ oscale, int n) {
    __shared__ float sW[1024];
    __shared__ float sb[32];
    __shared__ int sidx[SLDS];
    for (int i = threadIdx.x; i < 1024; i += 256) sW[i] = W[i];
    if (threadIdx.x < 32) sb[threadIdx.x] = bias[threadIdx.x];
    int d0 = blockIdx.x * 64;
    int dEnd = min(d0 + 64, n);
    int E0;
    bool fits = stage_csr(csr, e_start, d0, dEnd, sidx, E0);
    int d = d0 + (threadIdx.x >> 2), sub = threadIdx.x & 3;
    int lane = threadIdx.x & 63;
    if (d >= n) return;
    int e0 = e_start[d];
    int cnt = e_start[d + 1] - e0;
    float acc[8];
    gather_f8(u8, uscale, sidx, fits, csr, e0, e0 - E0, cnt, d, sub, acc);
    float dv = dinv[d];
    float vr[8];
#pragma unroll
    for (int i = 0; i < 8; i++) vr[i] = fmaxf(dv * acc[i] + sb[sub * 8 + i], 0.f);
    float o[8];
#pragma unroll
    for (int i = 0; i < 8; i++) o[i] = 0.f;
    mm32_8(sW, vr, sub, lane, o);
#pragma unroll
    for (int i = 0; i < 8; i++) o[i] *= dv;
    store_f8(o8, oscale, d, sub, o);
}

// agg3: v=relu(dv*acc+b3) -> hb (bf16, NT); theta head (NT store).
__global__ void __launch_bounds__(256) agg3_kernel(
                            const unsigned char* __restrict__ u8, const unsigned char* __restrict__ uscale,
                            const int* __restrict__ e_start, const unsigned* __restrict__ csr,
                            const float* __restrict__ dinv, const float* __restrict__ bias,
                            const float* __restrict__ Wt1, const float* __restrict__ bt1,
                            const float* __restrict__ Wt2, const float* __restrict__ bt2,
                            unsigned short* __restrict__ hb, float* __restrict__ theta, int n) {
    __shared__ float sW[1024];
    __shared__ float sb[32], sbt[32], sw2[32];
    __shared__ int sidx[SLDS];
    for (int i = threadIdx.x; i < 1024; i += 256) sW[i] = Wt1[i];
    if (threadIdx.x < 32) {
        sb[threadIdx.x] = bias[threadIdx.x];
        sbt[threadIdx.x] = bt1[threadIdx.x];
        sw2[threadIdx.x] = Wt2[threadIdx.x];
    }
    int d0 = blockIdx.x * 64;
    int dEnd = min(d0 + 64, n);
    int E0;
    bool fits = stage_csr(csr, e_start, d0, dEnd, sidx, E0);
    int d = d0 + (threadIdx.x >> 2), sub = threadIdx.x & 3;
    int lane = threadIdx.x & 63;
    if (d >= n) return;
    int e0 = e_start[d];
    int cnt = e_start[d + 1] - e0;
    float acc[8];
    gather_f8(u8, uscale, sidx, fits, csr, e0, e0 - E0, cnt, d, sub, acc);
    float dv = dinv[d];
    float vr[8];
#pragma unroll
    for (int i = 0; i < 8; i++) vr[i] = fmaxf(dv * acc[i] + sb[sub * 8 + i], 0.f);
    uvec4 st;
    st.x = bfpack(vr[0], vr[1]);
    st.y = bfpack(vr[2], vr[3]);
    st.z = bfpack(vr[4], vr[5]);
    st.w = bfpack(vr[6], vr[7]);
    __builtin_nontemporal_store(st, (uvec4*)hb + (size_t)d * 4 + sub);
    float o[8];
#pragma unroll
    for (int i = 0; i < 8; i++) o[i] = 0.f;
    mm32_8(sW, vr, sub, lane, o);
    float tl = 0.f;
#pragma unroll
    for (int i = 0; i < 8; i++)
        tl += fmaxf(o[i] + sbt[sub * 8 + i], 0.f) * sw2[sub * 8 + i];
    tl += __shfl_xor(tl, 1, 64);
    tl += __shfl_xor(tl, 2, 64);
    if (sub == 0) __builtin_nontemporal_store(PI_F / (1.f + __expf(-(tl + bt2[0]))), theta + d);
}

// ---------------- pooled head: block-per-graph reduce ----------------

__global__ void __launch_bounds__(512) bg_kernel(
                          const unsigned short* __restrict__ hb, const int* __restrict__ gstart,
                          const float* __restrict__ Wg1, const float* __restrict__ bg1v,
                          const float* __restrict__ Wg2, const float* __restrict__ bg2v,
                          float* __restrict__ out, int G) {
    __shared__ float sW[1024];
    __shared__ float part[8][32];
    for (int i = threadIdx.x; i < 1024; i += 512) sW[i] = Wg1[i];
    int g = blockIdx.x;
    int s = gstart[g], e = gstart[g + 1];
    int w = threadIdx.x >> 6;
    int lane = threadIdx.x & 63;
    int f = lane & 31, h = lane >> 5;
    float a = 0.f;
    for (int i = s + (w << 1) + h; i < e; i += 16)
        a += __uint_as_float((unsigned)hb[((size_t)i << 5) + f] << 16);
    a += __shfl_xor(a, 32, 64);
    if (h == 0) part[w][f] = a;
    __syncthreads();
    if (w == 0) {
        float hv = 0.f;
#pragma unroll
        for (int p = 0; p < 8; p++) hv += part[p][f];
        hv /= fmaxf((float)(e - s), 1.f);
        int base = lane & 32;
        float acc = bg1v[f];
#pragma unroll
        for (int k = 0; k < 32; k++) acc += __shfl(hv, base | k, 64) * sW[k * 32 + f];
        acc = fmaxf(acc, 0.f);
        float p0 = acc * Wg2[f * 2 + 0];
        float p1 = acc * Wg2[f * 2 + 1];
#pragma unroll
        for (int m = 1; m < 32; m <<= 1) {
            p0 += __shfl_xor(p0, m, 64);
            p1 += __shfl_xor(p1, m, 64);
        }
        if (f == 0) {
            out[g * 2 + 0] = 2.f * PI_F / (1.f + __expf(-(p0 + bg2v[0])));
            out[g * 2 + 1] = 2.f * PI_F / (1.f + __expf(-(p1 + bg2v[1])));
        }
    }
}

// ---------------- launch ----------------

extern "C" void kernel_launch(void* const* d_in, const int* in_sizes, int n_in,
                              void* d_out, int out_size, void* d_ws, size_t ws_size,
                              hipStream_t stream) {
    const float* x   = (const float*)d_in[0];
    const int*   ei  = (const int*)d_in[1];
    const int* batch = (const int*)d_in[2];
    const float* W1  = (const float*)d_in[3];
    const float* b1  = (const float*)d_in[4];
    const float* W2  = (const float*)d_in[5];
    const float* b2  = (const float*)d_in[6];
    const float* W3  = (const float*)d_in[7];
    const float* b3  = (const float*)d_in[8];
    const float* Wt1 = (const float*)d_in[9];
    const float* bt1 = (const float*)d_in[10];
    const float* Wt2 = (const float*)d_in[11];
    const float* bt2 = (const float*)d_in[12];
    const float* Wg1 = (const float*)d_in[13];
    const float* bg1 = (const float*)d_in[14];
    const float* Wg2 = (const float*)d_in[15];
    const float* bg2 = (const float*)d_in[16];

    const int N = in_sizes[0];
    const int E = in_sizes[1] / 2;
    const int G = 128;
    const int* src = ei;
    const int* dst = ei + E;
    float* theta_out = (float*)d_out;
    float* bg_out = (float*)d_out + N;

    const int NB2 = (N + BSZ - 1) >> BSH;
    const int CHUNK = (E + NBLK - 1) / NBLK;

    char* w = (char*)d_ws;
    auto alloc = [&](size_t bytes) -> char* { char* p = w; w += align256(bytes); return p; };
    int*      C        = (int*)alloc((size_t)NBLK * NB2 * 4);
    int*      colsum   = (int*)alloc((size_t)NB2 * 4);
    int*      bbase    = (int*)alloc((size_t)(NB2 + 1) * 4);
    unsigned* bkt_data = (unsigned*)alloc((size_t)E * 4);
    unsigned* csr      = (unsigned*)alloc((size_t)E * 4);
    int*      e_start  = (int*)alloc((size_t)(N + 1) * 4);
    float*    dinv     = (float*)alloc((size_t)N * 4);
    float*    xd       = (float*)alloc((size_t)N * 4);
    unsigned char* u2  = (unsigned char*)alloc((size_t)N * 32);
    unsigned char* us2 = (unsigned char*)alloc((size_t)N);
    unsigned char* u3  = (unsigned char*)alloc((size_t)N * 32);
    unsigned char* us3 = (unsigned char*)alloc((size_t)N);
    unsigned short* hb = (unsigned short*)alloc((size_t)N * 64);
    int*      gstart   = (int*)alloc((size_t)(G + 1) * 4);

    size_t ldsB = (size_t)NB2 * 4;
    count_kernel<<<NBLK, 1024, ldsB, stream>>>(dst, C, E, CHUNK, NB2);
    scan_blocks_kernel<<<NB2, NBLK, 0, stream>>>(C, colsum, NB2);
    scan_totals_kernel<<<1, 256, 0, stream>>>(colsum, bbase, NB2, E);
    scatter_kernel<<<NBLK, 1024, ldsB, stream>>>(src, dst, C, bbase, bkt_data, E, CHUNK, NB2);
    csr_build_kernel<<<NB2, 512, 0, stream>>>(bkt_data, bbase, x, csr, e_start, dinv, xd,
                                              batch, gstart, N, NB2, G);

    unsigned gridQ = (unsigned)(((size_t)N * 4 + 255) / 256);   // 4 threads per node

    agg1_kernel<<<gridQ, 256, 0, stream>>>(xd, e_start, csr, dinv, W1, b1, W2, u2, us2, N);
    agg2_kernel<<<gridQ, 256, 0, stream>>>(u2, us2, e_start, csr, dinv, b2, W3, u3, us3, N);
    agg3_kernel<<<gridQ, 256, 0, stream>>>(u3, us3, e_start, csr, dinv, b3,
                                           Wt1, bt1, Wt2, bt2, hb, theta_out, N);

    bg_kernel<<<G, 512, 0, stream>>>(hb, gstart, Wg1, bg1, Wg2, bg2, bg_out, G);
}